// Round 2
// baseline (1454.579 us; speedup 1.0000x reference)
//
#include <hip/hip_runtime.h>
#include <math.h>

#define SZ1 4096
#define SZ2 4096
#define EMBD 32
#define KNN 20
#define HID 64
#define SELCAP 192

// ---------------------------------------------------------------------------
// Kernel 0: row norms ||e_j||^2 for both embedding tables (once, tiny).
// ---------------------------------------------------------------------------
__global__ __launch_bounds__(256) void norms_kernel(
    const float* __restrict__ emb1, const float* __restrict__ emb2,
    float* __restrict__ norms)
{
    const int j = blockIdx.x * 256 + threadIdx.x;   // 0..8191
    const float* emb = (j < SZ1) ? emb1 : emb2;
    const int r = j & (SZ1 - 1);
    const float4* row = (const float4*)(emb + (size_t)r * EMBD);
    float ee = 0.f;
#pragma unroll
    for (int d = 0; d < 8; ++d) {
        float4 e = row[d];
        ee += e.x * e.x + e.y * e.y + e.z * e.z + e.w * e.w;
    }
    norms[j] = ee;
}

// ---------------------------------------------------------------------------
// Shared state for histogram top-K selection.
// ---------------------------------------------------------------------------
struct SelShared {
    unsigned int hist[256];
    float        cand_d2[SELCAP];
    int          cand_i[SELCAP];
    float        red_mn[4], red_mx[4];
    unsigned int wsum[4];
    unsigned int bc_b, bc_cumb, bc_prev, ncand;
};

// Select the 20 smallest d2c[] values across the block (4096 candidates held
// 16-per-thread in registers). Data-driven linear histogram with refinement
// into the boundary bin; compact <=SELCAP candidates; one wave finishes with
// barrier-free shfl argmin passes.
__device__ __forceinline__ void select20(
    float (&d2c)[16], int qidx, SelShared& sh,
    int tid, int lane, int wid,
    int* __restrict__ nb_out, float* __restrict__ w_out)
{
    unsigned int alive = 0xFFFFu;
    if (tid == (qidx & 255)) alive &= ~(1u << (qidx >> 8));   // exclude self
    unsigned int cand = 0u;

    // --- block min/max of candidate d2 ---
    float mn = 1e30f, mx = -1e30f;
#pragma unroll
    for (int r = 0; r < 16; ++r)
        if (alive & (1u << r)) { mn = fminf(mn, d2c[r]); mx = fmaxf(mx, d2c[r]); }
#pragma unroll
    for (int off = 32; off; off >>= 1) {
        mn = fminf(mn, __shfl_xor(mn, off, 64));
        mx = fmaxf(mx, __shfl_xor(mx, off, 64));
    }
    if (lane == 0) { sh.red_mn[wid] = mn; sh.red_mx[wid] = mx; }
    __syncthreads();
    mn = fminf(fminf(sh.red_mn[0], sh.red_mn[1]), fminf(sh.red_mn[2], sh.red_mn[3]));
    mx = fmaxf(fmaxf(sh.red_mx[0], sh.red_mx[1]), fmaxf(sh.red_mx[2], sh.red_mx[3]));

    float lo = mn;
    float binw = (mx - mn) * (1.f / 256.f);
    unsigned int base = 0;
    bool done = false;

    for (int lvl = 0; lvl < 6 && !done; ++lvl) {
        const float scale = (binw > 0.f) ? (1.f / binw) : 0.f;
        sh.hist[tid] = 0;
        __syncthreads();
#pragma unroll
        for (int r = 0; r < 16; ++r)
            if (alive & (1u << r)) {
                float bf = fminf(fmaxf((d2c[r] - lo) * scale, 0.f), 255.f);
                atomicAdd(&sh.hist[(int)bf], 1u);
            }
        __syncthreads();

        // block-wide inclusive scan over 256 bins
        unsigned int h = sh.hist[tid];
        unsigned int c = h;
#pragma unroll
        for (int off = 1; off < 64; off <<= 1) {
            unsigned int n = __shfl_up(c, off, 64);
            if (lane >= off) c += n;
        }
        if (lane == 63) sh.wsum[wid] = c;
        __syncthreads();
        if (wid > 0) c += sh.wsum[0];
        if (wid > 1) c += sh.wsum[1];
        if (wid > 2) c += sh.wsum[2];
        const unsigned int ct = base + c;
        if (ct >= KNN && (ct - h) < KNN) {   // unique: first bin crossing 20
            sh.bc_b = (unsigned int)tid; sh.bc_cumb = ct; sh.bc_prev = ct - h;
        }
        __syncthreads();
        const int b = (int)sh.bc_b;
        const unsigned int cumb = sh.bc_cumb;
        const unsigned int prevc = sh.bc_prev;

        // split candidates: bin<b definite, bin==b stays alive, bin>b drops
#pragma unroll
        for (int r = 0; r < 16; ++r)
            if (alive & (1u << r)) {
                float bf = fminf(fmaxf((d2c[r] - lo) * scale, 0.f), 255.f);
                int bin = (int)bf;
                if (bin < b)      { cand |= (1u << r); alive &= ~(1u << r); }
                else if (bin > b) { alive &= ~(1u << r); }
            }

        if (cumb <= SELCAP) { cand |= alive; done = true; }
        else {
            base = prevc;
            lo = lo + (float)b * binw;
            binw *= (1.f / 256.f);
            if (binw < 1e-37f) { cand |= alive; done = true; }  // exact ties
        }
        __syncthreads();   // protect hist/bc reuse next level
    }
    if (!done) cand |= alive;   // pathological fallback (ties)

    __syncthreads();
    if (tid == 0) sh.ncand = 0;
    __syncthreads();
#pragma unroll
    for (int r = 0; r < 16; ++r)
        if (cand & (1u << r)) {
            unsigned int slot = atomicAdd(&sh.ncand, 1u);
            if (slot < SELCAP) {
                sh.cand_d2[slot] = d2c[r];
                sh.cand_i[slot]  = (r << 8) + tid;
            }
        }
    __syncthreads();

    // --- wave 0: barrier-free top-20 over <=SELCAP candidates ---
    if (wid == 0) {
        int cnt = (int)sh.ncand; if (cnt > SELCAP) cnt = SELCAP;
        float va = (lane < cnt)        ? sh.cand_d2[lane]       : 1e30f;
        float vb = (lane + 64 < cnt)   ? sh.cand_d2[lane + 64]  : 1e30f;
        float vc = (lane + 128 < cnt)  ? sh.cand_d2[lane + 128] : 1e30f;
        float kd2 = 0.f; int ks = 0;
#pragma unroll
        for (int k = 0; k < KNN; ++k) {
            float bv = va; int bs = lane;
            if (vb < bv) { bv = vb; bs = lane + 64; }
            if (vc < bv) { bv = vc; bs = lane + 128; }
#pragma unroll
            for (int off = 32; off; off >>= 1) {
                float ov = __shfl_xor(bv, off, 64);
                int   os = __shfl_xor(bs, off, 64);
                if (ov < bv || (ov == bv && os < bs)) { bv = ov; bs = os; }
            }
            if (lane == (bs & 63)) {          // kill winner slot
                if (bs < 64) va = 1e30f; else if (bs < 128) vb = 1e30f; else vc = 1e30f;
            }
            if (lane == k) { kd2 = bv; ks = bs; }
        }
        if (lane < KNN) {
            nb_out[lane] = sh.cand_i[ks];
            w_out[lane]  = expf(-(sqrtf(kd2) + 0.001f));   // TAU = 1
        }
    }
}

// ---------------------------------------------------------------------------
// Kernel 1: KNN, 2 queries per 256-thread block (halves the L2 emb stream).
// Distances kept in registers (16/thread/query); norms precomputed.
// ---------------------------------------------------------------------------
__global__ __launch_bounds__(256) void knn2_kernel(
    const float* __restrict__ emb1, const float* __restrict__ emb2,
    const float* __restrict__ norms,
    int* __restrict__ nbr, float* __restrict__ wv)
{
    const int g0     = blockIdx.x * 2;
    const int branch = g0 >> 12;            // 0 -> emb1, 1 -> emb2
    const int i0     = g0 & 4095;           // even
    const int i1     = i0 + 1;
    const float* emb = branch ? emb2 : emb1;
    const float* nrm = norms + branch * SZ1;
    const int tid  = threadIdx.x;
    const int lane = tid & 63;
    const int wid  = tid >> 6;

    __shared__ float4 qs[16];
    __shared__ SelShared sh;

    if (tid < 16)
        qs[tid] = ((const float4*)(emb + (size_t)(i0 + (tid >> 3)) * EMBD))[tid & 7];
    __syncthreads();

    float4 q0[8], q1[8];
#pragma unroll
    for (int d = 0; d < 8; ++d) { q0[d] = qs[d]; q1[d] = qs[8 + d]; }
    const float qq0 = nrm[i0];
    const float qq1 = nrm[i1];

    float d2c0[16], d2c1[16];
#pragma unroll
    for (int r = 0; r < 16; ++r) {
        const int j = (r << 8) + tid;
        const float4* row = (const float4*)(emb + (size_t)j * EMBD);
        float dot0 = 0.f, dot1 = 0.f;
#pragma unroll
        for (int d = 0; d < 8; ++d) {
            float4 e = row[d];
            dot0 += e.x * q0[d].x + e.y * q0[d].y + e.z * q0[d].z + e.w * q0[d].w;
            dot1 += e.x * q1[d].x + e.y * q1[d].y + e.z * q1[d].z + e.w * q1[d].w;
        }
        const float ee = nrm[j];
        d2c0[r] = fmaxf(qq0 + ee - 2.f * dot0, 0.f);
        d2c1[r] = fmaxf(qq1 + ee - 2.f * dot1, 0.f);
    }

    int*   nb0 = nbr + ((size_t)branch * SZ1 + i0) * KNN;
    float* w0  = wv  + ((size_t)branch * SZ1 + i0) * KNN;
    select20(d2c0, i0, sh, tid, lane, wid, nb0, w0);
    select20(d2c1, i1, sh, tid, lane, wid, nb0 + KNN, w0 + KNN);
}

// ---------------------------------------------------------------------------
// Kernel 2: per-sample gather + feature reduction + MLP (unchanged).
// ---------------------------------------------------------------------------
__global__ __launch_bounds__(256) void feat_mlp_kernel(
    const int* __restrict__ time, const int* __restrict__ idx1,
    const int* __restrict__ idx2,
    const float* __restrict__ residuals, const float* __restrict__ means,
    const float* __restrict__ stds,
    const int* __restrict__ nbr, const float* __restrict__ wv,
    const float* __restrict__ W1, const float* __restrict__ b1,
    const float* __restrict__ Wm, const float* __restrict__ bm,
    const float* __restrict__ Ws, const float* __restrict__ bs,
    float* __restrict__ out, int B)
{
    const int wave = threadIdx.x >> 6;
    const int lane = threadIdx.x & 63;
    const int s    = blockIdx.x * 4 + wave;
    if (s >= B) return;

    const int t  = time[s];
    const int i1 = idx1[s];
    const int i2 = idx2[s];
    const size_t base = (size_t)t * SZ1 * SZ2;

    const int half = lane >> 5;   // 0: f1 (emb1/index1), 1: f2 (emb2/index2)
    const int k    = lane & 31;

    float y = 0.f, w = 0.f;
    if (k < KNN) {
        if (half == 0) {
            const size_t o = ((size_t)0 * SZ1 + i1) * KNN + k;
            const int nb = nbr[o];
            y = residuals[base + (size_t)nb * SZ2 + i2];
            w = wv[o];
        } else {
            const size_t o = ((size_t)1 * SZ1 + i2) * KNN + k;
            const int nb = nbr[o];
            y = residuals[base + (size_t)i1 * SZ2 + nb];
            w = wv[o];
        }
    }

    float wy = w * y, sw = w, sy = y;
#pragma unroll
    for (int off = 16; off; off >>= 1) {
        wy += __shfl_xor(wy, off, 32);
        sw += __shfl_xor(sw, off, 32);
        sy += __shfl_xor(sy, off, 32);
    }
    const float m   = sy * (1.f / KNN);
    float dev = (k < KNN) ? (y - m) : 0.f;
    float ss  = dev * dev;
#pragma unroll
    for (int off = 16; off; off >>= 1) ss += __shfl_xor(ss, off, 32);

    const float wmean = wy / sw;
    const float sd    = sqrtf(ss * (1.f / (KNN - 1)));  // ddof=1

    const float f_wm1 = __shfl(wmean, 0, 64);
    const float f_sw1 = __shfl(sw,    0, 64);
    const float f_sd1 = __shfl(sd,    0, 64);
    const float f_wm2 = __shfl(wmean, 32, 64);
    const float f_sw2 = __shfl(sw,    32, 64);
    const float f_sd2 = __shfl(sd,    32, 64);

    const float mn  = means[base + (size_t)i1 * SZ2 + i2];
    const float sdv = stds [base + (size_t)i1 * SZ2 + i2];

    const float feats[8] = { f_wm1, f_sw1, f_sd1, f_wm2, f_sw2, f_sd2, mn, sdv };

    const float* wrow = W1 + lane * 8;
    float h = b1[lane];
#pragma unroll
    for (int f = 0; f < 8; ++f) h += feats[f] * wrow[f];
    h = fmaxf(h, 0.f);

    float mo = h * Wm[lane];
    float so = h * Ws[lane];
#pragma unroll
    for (int off = 32; off; off >>= 1) {
        mo += __shfl_xor(mo, off, 64);
        so += __shfl_xor(so, off, 64);
    }
    if (lane == 0) {
        out[s]     = mo + bm[0];
        out[B + s] = so + bs[0];
    }
}

extern "C" void kernel_launch(void* const* d_in, const int* in_sizes, int n_in,
                              void* d_out, int out_size, void* d_ws, size_t ws_size,
                              hipStream_t stream)
{
    const int*   time      = (const int*)d_in[0];
    const int*   idx1      = (const int*)d_in[1];
    const int*   idx2      = (const int*)d_in[2];
    const float* residuals = (const float*)d_in[3];
    const float* means     = (const float*)d_in[4];
    const float* stds      = (const float*)d_in[5];
    const float* emb1      = (const float*)d_in[6];
    const float* emb2      = (const float*)d_in[7];
    const float* W1        = (const float*)d_in[8];
    const float* b1        = (const float*)d_in[9];
    const float* Wm        = (const float*)d_in[10];
    const float* bm        = (const float*)d_in[11];
    const float* Ws        = (const float*)d_in[12];
    const float* bs        = (const float*)d_in[13];
    float* out = (float*)d_out;

    const int B = in_sizes[0];

    // workspace: nbr [2][4096][20] i32 | wv [2][4096][20] f32 | norms [2][4096] f32
    const size_t NBR_BYTES = (size_t)2 * SZ1 * KNN * sizeof(int);
    int*   nbr   = (int*)d_ws;
    float* wv    = (float*)((char*)d_ws + NBR_BYTES);
    float* norms = (float*)((char*)d_ws + 2 * NBR_BYTES);

    norms_kernel<<<(2 * SZ1) / 256, 256, 0, stream>>>(emb1, emb2, norms);
    knn2_kernel<<<SZ1, 256, 0, stream>>>(emb1, emb2, norms, nbr, wv);
    feat_mlp_kernel<<<(B + 3) / 4, 256, 0, stream>>>(
        time, idx1, idx2, residuals, means, stds, nbr, wv,
        W1, b1, Wm, bm, Ws, bs, out, B);
}

// Round 5
// 999.531 us; speedup vs baseline: 1.4553x; 1.4553x over previous
//
#include <hip/hip_runtime.h>
#include <math.h>

#define SZ1 4096
#define SZ2 4096
#define EMBD 32
#define KNN 20
#define HID 64
#define SELCAP 192

// ---------------------------------------------------------------------------
// Kernel 1: per (branch, query) top-20 nearest neighbors.
// One 256-thread block per query. d^2 for all 4096 candidates in LDS
// (16 KB, stride-1 = conflict-free), then a data-driven 256-bin histogram
// select (typically ONE level), compaction to <=SELCAP candidates, and a
// single-wave barrier-free top-20 finish.
// Register discipline (round-2 lesson: 256 VGPR + 509 MB scratch spills):
//   - NO register-resident distance arrays (LDS instead)
//   - #pragma unroll 1 on the row loop (stops load hoisting)
//   - __launch_bounds__(256, 4) caps the allocator at 128 VGPRs
// ---------------------------------------------------------------------------
__global__ __launch_bounds__(256, 4) void knn_kernel(
    const float* __restrict__ emb1, const float* __restrict__ emb2,
    int* __restrict__ nbr, float* __restrict__ wv)
{
    const int bid    = blockIdx.x;
    const int branch = bid >> 12;        // 0 -> emb1, 1 -> emb2
    const int i      = bid & 4095;
    const float* emb = branch ? emb2 : emb1;
    const int tid  = threadIdx.x;
    const int lane = tid & 63;
    const int wid  = tid >> 6;

    __shared__ float        sim[4096];      // 16 KB: d^2 per candidate
    __shared__ float4       qs[8];
    __shared__ unsigned int hist[256];
    __shared__ float        cand_d2[SELCAP];
    __shared__ int          cand_i[SELCAP];
    __shared__ float        red_mn[4], red_mx[4];
    __shared__ unsigned int wsum[4];
    __shared__ unsigned int bc_b, bc_cumb, bc_prev, ncand;

    if (tid < 8) qs[tid] = ((const float4*)(emb + (size_t)i * EMBD))[tid];
    __syncthreads();

    float4 q[8];
    float qq = 0.f;
#pragma unroll
    for (int d = 0; d < 8; ++d) {
        q[d] = qs[d];
        qq += q[d].x * q[d].x + q[d].y * q[d].y + q[d].z * q[d].z + q[d].w * q[d].w;
    }

    // --- distance phase: each thread owns rows j = tid + 256*r ---
    float mn = 1e30f, mx = -1e30f;
#pragma unroll 1
    for (int r = 0; r < 16; ++r) {
        const int j = (r << 8) + tid;
        const float4* row = (const float4*)(emb + (size_t)j * EMBD);
        float dot = 0.f, ee = 0.f;
#pragma unroll
        for (int d = 0; d < 8; ++d) {
            float4 e = row[d];
            dot += e.x * q[d].x + e.y * q[d].y + e.z * q[d].z + e.w * q[d].w;
            ee  += e.x * e.x + e.y * e.y + e.z * e.z + e.w * e.w;
        }
        float d2 = fmaxf(qq + ee - 2.f * dot, 0.f);
        if (j == i) d2 = 1e30f;              // exclude self
        else { mn = fminf(mn, d2); mx = fmaxf(mx, d2); }
        sim[j] = d2;
    }

    // --- block min/max ---
#pragma unroll
    for (int off = 32; off; off >>= 1) {
        mn = fminf(mn, __shfl_xor(mn, off, 64));
        mx = fmaxf(mx, __shfl_xor(mx, off, 64));
    }
    if (lane == 0) { red_mn[wid] = mn; red_mx[wid] = mx; }
    __syncthreads();
    mn = fminf(fminf(red_mn[0], red_mn[1]), fminf(red_mn[2], red_mn[3]));
    mx = fmaxf(fmaxf(red_mx[0], red_mx[1]), fmaxf(red_mx[2], red_mx[3]));

    // --- histogram select: find a value window holding ranks [1..~SELCAP] ---
    float lo = mn;
    float binw = (mx - mn) * (1.f / 256.f);
    float hi = mn + binw * 256.f;
    unsigned int base = 0;           // #values strictly below current window
    int done = 0;                    // 1: compact bins<=b, else: window-cap

    for (int lvl = 0; lvl < 6; ++lvl) {
        if (binw <= 0.f) break;      // degenerate (ties) -> window-cap path
        const float scale = 1.f / binw;
        hist[tid] = 0;
        if (tid == 0) bc_b = 0xFFFFFFFFu;
        __syncthreads();
        for (int r = 0; r < 16; ++r) {
            const float v = sim[(r << 8) + tid];
            if (v >= lo && v < hi) {
                int b = (int)fminf((v - lo) * scale, 255.f);
                atomicAdd(&hist[b], 1u);
            }
        }
        __syncthreads();
        const unsigned int h = hist[tid];
        unsigned int c = h;
#pragma unroll
        for (int off = 1; off < 64; off <<= 1) {
            unsigned int n = __shfl_up(c, off, 64);
            if (lane >= off) c += n;
        }
        if (lane == 63) wsum[wid] = c;
        __syncthreads();
        if (wid > 0) c += wsum[0];
        if (wid > 1) c += wsum[1];
        if (wid > 2) c += wsum[2];
        const unsigned int ct = base + c;
        if (ct >= KNN && (ct - h) < KNN) {   // unique bin crossing rank 20
            bc_b = (unsigned int)tid; bc_cumb = ct; bc_prev = ct - h;
        }
        __syncthreads();
        if (bc_b == 0xFFFFFFFFu) break;      // fp pathological -> window-cap
        if (bc_cumb <= SELCAP) { done = 1; break; }
        // refine into the boundary bin
        base = bc_prev;
        lo   = lo + (float)bc_b * binw;
        hi   = lo + binw;
        binw *= (1.f / 256.f);
        __syncthreads();                     // protect hist/bc reuse
    }

    const int   b_fin     = (done == 1) ? (int)bc_b : 256;
    const float scale_fin = (binw > 0.f) ? (1.f / binw) : 0.f;

    __syncthreads();
    if (tid == 0) ncand = 0;
    __syncthreads();

    // --- compaction: gather candidate set (superset of true top-20) ---
    for (int r = 0; r < 16; ++r) {
        const int j = (r << 8) + tid;
        const float v = sim[j];
        bool take;
        if (done == 1)
            take = (v < lo) ||
                   (v < hi && (int)fminf((v - lo) * scale_fin, 255.f) <= b_fin);
        else
            take = (v <= hi);                // fallback: cap at SELCAP
        if (take) {
            unsigned int slot = atomicAdd(&ncand, 1u);
            if (slot < SELCAP) { cand_d2[slot] = v; cand_i[slot] = j; }
        }
    }
    __syncthreads();

    // --- wave 0: barrier-free top-20 over <=SELCAP candidates ---
    if (wid == 0) {
        int cnt = (int)ncand; if (cnt > SELCAP) cnt = SELCAP;
        float va = (lane < cnt)       ? cand_d2[lane]       : 1e30f;
        float vb = (lane + 64 < cnt)  ? cand_d2[lane + 64]  : 1e30f;
        float vc = (lane + 128 < cnt) ? cand_d2[lane + 128] : 1e30f;
        int*   nb_out = nbr + ((size_t)branch * SZ1 + i) * KNN;
        float* w_out  = wv  + ((size_t)branch * SZ1 + i) * KNN;
        float kd2 = 0.f; int ks = 0;
#pragma unroll 1
        for (int k = 0; k < KNN; ++k) {
            float bv = va; int bs = lane;
            if (vb < bv) { bv = vb; bs = lane + 64; }
            if (vc < bv) { bv = vc; bs = lane + 128; }
#pragma unroll
            for (int off = 32; off; off >>= 1) {
                float ov = __shfl_xor(bv, off, 64);
                int   os = __shfl_xor(bs, off, 64);
                if (ov < bv || (ov == bv && os < bs)) { bv = ov; bs = os; }
            }
            if (lane == (bs & 63)) {         // kill winner slot
                if (bs < 64) va = 1e30f; else if (bs < 128) vb = 1e30f; else vc = 1e30f;
            }
            if (lane == k) { kd2 = bv; ks = bs; }
        }
        if (lane < KNN) {
            nb_out[lane] = cand_i[ks];
            w_out[lane]  = expf(-(sqrtf(kd2) + 0.001f));   // TAU = 1
        }
    }
}

// ---------------------------------------------------------------------------
// Kernel 2: per-sample gather + feature reduction + MLP (unchanged).
// One 64-lane wave per sample (4 samples / 256-thread block).
// ---------------------------------------------------------------------------
__global__ __launch_bounds__(256) void feat_mlp_kernel(
    const int* __restrict__ time, const int* __restrict__ idx1,
    const int* __restrict__ idx2,
    const float* __restrict__ residuals, const float* __restrict__ means,
    const float* __restrict__ stds,
    const int* __restrict__ nbr, const float* __restrict__ wv,
    const float* __restrict__ W1, const float* __restrict__ b1,
    const float* __restrict__ Wm, const float* __restrict__ bm,
    const float* __restrict__ Ws, const float* __restrict__ bs,
    float* __restrict__ out, int B)
{
    const int wave = threadIdx.x >> 6;
    const int lane = threadIdx.x & 63;
    const int s    = blockIdx.x * 4 + wave;
    if (s >= B) return;

    const int t  = time[s];
    const int i1 = idx1[s];
    const int i2 = idx2[s];
    const size_t base = (size_t)t * SZ1 * SZ2;

    const int half = lane >> 5;   // 0: f1 (emb1/index1), 1: f2 (emb2/index2)
    const int k    = lane & 31;

    float y = 0.f, w = 0.f;
    if (k < KNN) {
        if (half == 0) {
            const size_t o = ((size_t)0 * SZ1 + i1) * KNN + k;
            const int nb = nbr[o];
            y = residuals[base + (size_t)nb * SZ2 + i2];
            w = wv[o];
        } else {
            const size_t o = ((size_t)1 * SZ1 + i2) * KNN + k;
            const int nb = nbr[o];
            y = residuals[base + (size_t)i1 * SZ2 + nb];
            w = wv[o];
        }
    }

    float wy = w * y, sw = w, sy = y;
#pragma unroll
    for (int off = 16; off; off >>= 1) {
        wy += __shfl_xor(wy, off, 32);
        sw += __shfl_xor(sw, off, 32);
        sy += __shfl_xor(sy, off, 32);
    }
    const float m   = sy * (1.f / KNN);
    float dev = (k < KNN) ? (y - m) : 0.f;
    float ss  = dev * dev;
#pragma unroll
    for (int off = 16; off; off >>= 1) ss += __shfl_xor(ss, off, 32);

    const float wmean = wy / sw;
    const float sd    = sqrtf(ss * (1.f / (KNN - 1)));  // ddof=1

    const float f_wm1 = __shfl(wmean, 0, 64);
    const float f_sw1 = __shfl(sw,    0, 64);
    const float f_sd1 = __shfl(sd,    0, 64);
    const float f_wm2 = __shfl(wmean, 32, 64);
    const float f_sw2 = __shfl(sw,    32, 64);
    const float f_sd2 = __shfl(sd,    32, 64);

    const float mn  = means[base + (size_t)i1 * SZ2 + i2];
    const float sdv = stds [base + (size_t)i1 * SZ2 + i2];

    const float feats[8] = { f_wm1, f_sw1, f_sd1, f_wm2, f_sw2, f_sd2, mn, sdv };

    const float* wrow = W1 + lane * 8;
    float h = b1[lane];
#pragma unroll
    for (int f = 0; f < 8; ++f) h += feats[f] * wrow[f];
    h = fmaxf(h, 0.f);

    float mo = h * Wm[lane];
    float so = h * Ws[lane];
#pragma unroll
    for (int off = 32; off; off >>= 1) {
        mo += __shfl_xor(mo, off, 64);
        so += __shfl_xor(so, off, 64);
    }
    if (lane == 0) {
        out[s]     = mo + bm[0];
        out[B + s] = so + bs[0];
    }
}

extern "C" void kernel_launch(void* const* d_in, const int* in_sizes, int n_in,
                              void* d_out, int out_size, void* d_ws, size_t ws_size,
                              hipStream_t stream)
{
    const int*   time      = (const int*)d_in[0];
    const int*   idx1      = (const int*)d_in[1];
    const int*   idx2      = (const int*)d_in[2];
    const float* residuals = (const float*)d_in[3];
    const float* means     = (const float*)d_in[4];
    const float* stds      = (const float*)d_in[5];
    const float* emb1      = (const float*)d_in[6];
    const float* emb2      = (const float*)d_in[7];
    const float* W1        = (const float*)d_in[8];
    const float* b1        = (const float*)d_in[9];
    const float* Wm        = (const float*)d_in[10];
    const float* bm        = (const float*)d_in[11];
    const float* Ws        = (const float*)d_in[12];
    const float* bs        = (const float*)d_in[13];
    float* out = (float*)d_out;

    const int B = in_sizes[0];

    // workspace: nbr [2][4096][20] i32 | wv [2][4096][20] f32  (~1.3 MB)
    const size_t NBR_BYTES = (size_t)2 * SZ1 * KNN * sizeof(int);
    int*   nbr = (int*)d_ws;
    float* wv  = (float*)((char*)d_ws + NBR_BYTES);

    knn_kernel<<<2 * SZ1, 256, 0, stream>>>(emb1, emb2, nbr, wv);
    feat_mlp_kernel<<<(B + 3) / 4, 256, 0, stream>>>(
        time, idx1, idx2, residuals, means, stds, nbr, wv,
        W1, b1, Wm, bm, Ws, bs, out, B);
}